// Round 7
// baseline (494.258 us; speedup 1.0000x reference)
//
#include <hip/hip_runtime.h>

#define S_LEN 2048
#define HID 2048
#define NH 16
#define HD 128
#define QKV_N 3072   // 2048 q + 512 k + 512 v
#define KCOL 2048
#define VCOL 2560

typedef unsigned short ushort_t;
using bf16x8 = __attribute__((ext_vector_type(8))) __bf16;
using f32x4 = __attribute__((ext_vector_type(4))) float;
using ushort8 = __attribute__((ext_vector_type(8))) unsigned short;
using ushort4v = __attribute__((ext_vector_type(4))) unsigned short;

__device__ __forceinline__ unsigned short f2bf(float f) {
  unsigned int u = __float_as_uint(f);
  unsigned int r = u + 0x7FFFu + ((u >> 16) & 1u);
  return (unsigned short)(r >> 16);
}
__device__ __forceinline__ float bf2f(unsigned short h) {
  return __uint_as_float(((unsigned int)h) << 16);
}

__device__ __forceinline__ void gload_lds16(const ushort_t* g, ushort_t* lds) {
  __builtin_amdgcn_global_load_lds(
      (const __attribute__((address_space(1))) unsigned int*)g,
      (__attribute__((address_space(3))) unsigned int*)lds, 16, 0, 0);
}

// ---------------- fused cast fp32 -> bf16 for x, wq, wk, wv ----------------
__global__ void cast_fused_kernel(const float* __restrict__ x, const float* __restrict__ wq,
                                  const float* __restrict__ wk, const float* __restrict__ wv,
                                  ushort_t* __restrict__ xb, ushort_t* __restrict__ wqkv) {
  int i = blockIdx.x * 256 + threadIdx.x;  // float4 units, total 3670016
  const float* src;
  ushort_t* dst;
  int li;
  if (i < 2097152) { src = x; dst = xb; li = i; }
  else if (i < 3145728) { src = wq; dst = wqkv; li = i - 2097152; }
  else if (i < 3407872) { src = wk; dst = wqkv + 4194304; li = i - 3145728; }
  else { src = wv; dst = wqkv + 5242880; li = i - 3407872; }
  float4 v = reinterpret_cast<const float4*>(src)[li];
  ushort4v o;
  o.x = f2bf(v.x); o.y = f2bf(v.y); o.z = f2bf(v.z); o.w = f2bf(v.w);
  reinterpret_cast<ushort4v*>(dst)[li] = o;
}

// ---------------- wo cast (runs after QKV GEMM frees the buffer) ----------------
__global__ void cast_bf16_kernel(const float* __restrict__ in, ushort_t* __restrict__ out, int n4) {
  int i = blockIdx.x * 256 + threadIdx.x;
  if (i >= n4) return;
  float4 v = reinterpret_cast<const float4*>(in)[i];
  ushort4v o;
  o.x = f2bf(v.x); o.y = f2bf(v.y); o.z = f2bf(v.z); o.w = f2bf(v.w);
  reinterpret_cast<ushort4v*>(out)[i] = o;
}

// ---------------- fused vectorized RoPE (q: fold kw*scale; k: plain) ----------------
__global__ void rope_fused_kernel(ushort_t* __restrict__ qkv, const float* __restrict__ kw) {
  int idx = blockIdx.x * 256 + threadIdx.x;  // 524288 q-threads + 131072 k-threads
  int row, colbase, j0;
  float wsc;
  if (idx < 524288) {
    row = idx >> 7;
    int p = idx & 127;
    int h = p >> 3;
    j0 = (p & 7) * 8;
    colbase = h * HD;
    wsc = 0.08838834764831845f * kw[h];
  } else {
    int t = idx - 524288;
    row = t >> 5;
    int p = t & 31;
    int h = p >> 3;
    j0 = (p & 7) * 8;
    colbase = KCOL + h * HD;
    wsc = 1.0f;
  }
  int s = row & (S_LEN - 1);
  long base = (long)row * QKV_N + colbase;
  ushort8 x1 = *reinterpret_cast<const ushort8*>(qkv + base + j0);
  ushort8 x2 = *reinterpret_cast<const ushort8*>(qkv + base + j0 + 64);
  ushort8 o1, o2;
#pragma unroll
  for (int e = 0; e < 8; ++e) {
    int j = j0 + e;
    float inv = __expf(-(float)j * (9.210340371976184f / 64.0f));
    float ang = (float)s * inv;
    float sv, cv;
    sincosf(ang, &sv, &cv);
    float a = bf2f(x1[e]), bb = bf2f(x2[e]);
    o1[e] = f2bf((a * cv - bb * sv) * wsc);
    o2[e] = f2bf((a * sv + bb * cv) * wsc);
  }
  *reinterpret_cast<ushort8*>(qkv + base + j0) = o1;
  *reinterpret_cast<ushort8*>(qkv + base + j0 + 64) = o2;
}

// ---------------- V transpose: qkv V-region [4096][512] -> vt[b*512+vd][2048] ----------------
__global__ __launch_bounds__(256) void transpose_v_kernel(const ushort_t* __restrict__ qkv,
                                                          ushort_t* __restrict__ vt) {
  __shared__ ushort_t T[64][76];
  int bid = blockIdx.x;  // 512 = 64 token-tiles x 8 dim-tiles
  int dd = bid & 7;
  int tt = bid >> 3;
  int tid = threadIdx.x;
#pragma unroll
  for (int it = 0; it < 2; ++it) {
    int c = tid + it * 256;
    int i = c >> 3, j8 = c & 7;
    ushort8 v = *reinterpret_cast<const ushort8*>(
        qkv + (long)(tt * 64 + i) * QKV_N + VCOL + dd * 64 + j8 * 8);
    *reinterpret_cast<ushort8*>(&T[i][j8 * 8]) = v;
  }
  __syncthreads();
#pragma unroll
  for (int it = 0; it < 2; ++it) {
    int c = tid + it * 256;
    int jd = c >> 3, sc = c & 7;
    ushort8 o;
#pragma unroll
    for (int e = 0; e < 8; ++e) o[e] = T[sc * 8 + e][jd];
    int token = tt * 64 + sc * 8;
    int b = token >> 11, s = token & (S_LEN - 1);
    int vd = dd * 64 + jd;
    *reinterpret_cast<ushort8*>(vt + ((long)(b * 512 + vd) << 11) + s) = o;
  }
}

// ---------------- GEMM: C[M][N] = A[M][K] @ W[N][K]^T ----------------
__device__ __forceinline__ void store_c(ushort_t* p, float v) { *p = f2bf(v); }
__device__ __forceinline__ void store_c(float* p, float v) { *p = v; }

template <typename OT>
__global__ __launch_bounds__(256) void gemm_bt_kernel(const ushort_t* __restrict__ A,
                                                      const ushort_t* __restrict__ W,
                                                      OT* __restrict__ C, int M, int N, int K) {
  __shared__ ushort_t As[128 * 32];
  __shared__ ushort_t Bs[128 * 32];
  const int tid = threadIdx.x;
  const int l = tid & 63, w = tid >> 6;
  const int wr = w >> 1, wc = w & 1;
  const int r = l & 15, g = l >> 4;
  const long arow0 = (long)blockIdx.y * 128;
  const long brow0 = (long)blockIdx.x * 128;

  f32x4 acc[4][4] = {};

  const int c0 = tid, c1 = tid + 256;
  const ushort_t* a_src0 = A + (arow0 + (c0 >> 2)) * K + ((c0 & 3) << 3);
  const ushort_t* a_src1 = A + (arow0 + (c1 >> 2)) * K + ((c1 & 3) << 3);
  const ushort_t* b_src0 = W + (brow0 + (c0 >> 2)) * K + ((c0 & 3) << 3);
  const ushort_t* b_src1 = W + (brow0 + (c1 >> 2)) * K + ((c1 & 3) << 3);
  ushort_t* a_dst0 = &As[c0 * 8];
  ushort_t* a_dst1 = &As[c1 * 8];
  ushort_t* b_dst0 = &Bs[c0 * 8];
  ushort_t* b_dst1 = &Bs[c1 * 8];

  for (int kk = 0; kk < K; kk += 32) {
    gload_lds16(a_src0 + kk, a_dst0);
    gload_lds16(a_src1 + kk, a_dst1);
    gload_lds16(b_src0 + kk, b_dst0);
    gload_lds16(b_src1 + kk, b_dst1);
    __syncthreads();
    bf16x8 af[4], bw[4];
#pragma unroll
    for (int mi = 0; mi < 4; ++mi)
      af[mi] = *reinterpret_cast<const bf16x8*>(&As[(wr * 64 + mi * 16 + r) * 32 + g * 8]);
#pragma unroll
    for (int ni = 0; ni < 4; ++ni)
      bw[ni] = *reinterpret_cast<const bf16x8*>(&Bs[(wc * 64 + ni * 16 + r) * 32 + g * 8]);
#pragma unroll
    for (int mi = 0; mi < 4; ++mi)
#pragma unroll
      for (int ni = 0; ni < 4; ++ni)
        acc[mi][ni] = __builtin_amdgcn_mfma_f32_16x16x32_bf16(af[mi], bw[ni], acc[mi][ni], 0, 0, 0);
    __syncthreads();
  }

#pragma unroll
  for (int mi = 0; mi < 4; ++mi)
#pragma unroll
    for (int ni = 0; ni < 4; ++ni) {
      int col = (int)brow0 + wc * 64 + ni * 16 + r;
#pragma unroll
      for (int j = 0; j < 4; ++j) {
        int row = (int)arow0 + wr * 64 + mi * 16 + g * 4 + j;
        store_c(&C[(long)row * N + col], acc[mi][ni][j]);
      }
    }
}

// ---------------- causal GQA flash attention v3: barrier-free, L2-direct K/V ----
// KV is L2-resident (FETCH ~12MB, guide m169: don't LDS-stage cache-fit data).
// 512 blocks, 4 waves x 16 q-rows; each WAVE does q-tiles {qt, 31-qt} (balance).
// No __syncthreads anywhere; only per-wave Ps in LDS. XCD decode groups one
// kvh per XCD (K+V working set 2MB < 4MB L2).
__global__ __launch_bounds__(256, 2) void flash_attn_kernel(const ushort_t* __restrict__ qkv,
                                                            const ushort_t* __restrict__ Vt,
                                                            ushort_t* __restrict__ AO) {
  __shared__ ushort_t Ps[4][16 * 64];  // per-wave, XOR-swizzled 16B chunks

  const int bid0 = blockIdx.x;
  const int o = (bid0 & 7) * 64 + (bid0 >> 3);  // stride-8 HW XCD round-robin -> contiguous o per XCD
  const int pr = o & 15;
  const int hb = o >> 4;  // XCD x gets hb in [4x,4x+4): h={2x,2x+1} -> single kvh per XCD
  const int h = hb >> 1;
  const int b = hb & 1;
  const int tid = threadIdx.x;
  const int l = tid & 63, w = tid >> 6;
  const int r = l & 15, g = l >> 4;
  const int kvh = h >> 2;

  const ushort_t* Qb = qkv + (long)b * S_LEN * QKV_N + h * HD;
  const ushort_t* Kb = qkv + (long)b * S_LEN * QKV_N + KCOL + kvh * HD;
  const ushort_t* Vb = Vt + ((long)(b * 512 + kvh * HD) << 11);

  for (int pi = 0; pi < 2; ++pi) {
    const int qt = pi ? (31 - pr) : pr;
    const int qg = qt * 64 + w * 16;          // wave's first q row (batch-local)
    const long qrow0 = (long)b * S_LEN + qg;  // global token row (AO write only)

    bf16x8 qa[4];
#pragma unroll
    for (int ks = 0; ks < 4; ++ks)
      qa[ks] = *reinterpret_cast<const bf16x8*>(Qb + (long)(qg + r) * QKV_N + ks * 32 + g * 8);

    f32x4 acc[8] = {};
    float mrow[4], lrow[4];
#pragma unroll
    for (int j = 0; j < 4; ++j) { mrow[j] = -1e30f; lrow[j] = 0.f; }

    for (int kv = 0; kv <= qt; ++kv) {
      const ushort_t* Kt0 = Kb + (long)(kv * 64) * QKV_N;

      // ---- S = Q @ K^T (K fragments direct from L2)
      f32x4 s[4] = {};
      __builtin_amdgcn_s_setprio(1);
#pragma unroll
      for (int ks = 0; ks < 4; ++ks) {
        bf16x8 kf[4];
#pragma unroll
        for (int ni = 0; ni < 4; ++ni)
          kf[ni] = *reinterpret_cast<const bf16x8*>(
              Kt0 + (long)(ni * 16 + r) * QKV_N + ks * 32 + g * 8);
#pragma unroll
        for (int ni = 0; ni < 4; ++ni)
          s[ni] = __builtin_amdgcn_mfma_f32_16x16x32_bf16(qa[ks], kf[ni], s[ni], 0, 0, 0);
      }
      __builtin_amdgcn_s_setprio(0);

      // ---- causal mask on diagonal tile
      if (kv == qt) {
#pragma unroll
        for (int ni = 0; ni < 4; ++ni) {
          int key = kv * 64 + ni * 16 + r;
#pragma unroll
          for (int j = 0; j < 4; ++j) {
            int rowq = qg + g * 4 + j;
            if (key > rowq) s[ni][j] = -1e30f;
          }
        }
      }

      // ---- online softmax with defer-max (T13, THR=8)
      float mx[4];
      float dm = -1e30f;
#pragma unroll
      for (int j = 0; j < 4; ++j) {
        float m3 = fmaxf(fmaxf(s[0][j], s[1][j]), fmaxf(s[2][j], s[3][j]));
        m3 = fmaxf(m3, __shfl_xor(m3, 1));
        m3 = fmaxf(m3, __shfl_xor(m3, 2));
        m3 = fmaxf(m3, __shfl_xor(m3, 4));
        m3 = fmaxf(m3, __shfl_xor(m3, 8));
        mx[j] = m3;
        dm = fmaxf(dm, m3 - mrow[j]);
      }
      if (!__all(dm <= 8.0f)) {
#pragma unroll
        for (int j = 0; j < 4; ++j) {
          float mn = fmaxf(mrow[j], mx[j]);
          float ef = __expf(mrow[j] - mn);
          mrow[j] = mn;
          lrow[j] *= ef;
#pragma unroll
          for (int ni = 0; ni < 8; ++ni) acc[ni][j] *= ef;
        }
      }
#pragma unroll
      for (int j = 0; j < 4; ++j) {
        float ps = 0.f;
#pragma unroll
        for (int ni = 0; ni < 4; ++ni) {
          float p = __expf(s[ni][j] - mrow[j]);
          s[ni][j] = p;
          ps += p;
        }
        lrow[j] += ps;
      }

      // ---- P -> per-wave LDS (RTZ bf16; C layout -> A-frag layout, swizzled)
#pragma unroll
      for (int ni = 0; ni < 4; ++ni)
#pragma unroll
        for (int j = 0; j < 4; ++j) {
          int row = g * 4 + j;
          int chunk = (ni * 2 + (r >> 3)) ^ (row & 7);
          Ps[w][row * 64 + chunk * 8 + (r & 7)] =
              (ushort_t)(__float_as_uint(s[ni][j]) >> 16);
        }
      bf16x8 pa[2];
      pa[0] = *reinterpret_cast<const bf16x8*>(&Ps[w][r * 64 + (((g) ^ (r & 7)) << 3)]);
      pa[1] = *reinterpret_cast<const bf16x8*>(&Ps[w][r * 64 + (((4 + g) ^ (r & 7)) << 3)]);

      // ---- O += P @ V (V^T fragments direct from L2)
      __builtin_amdgcn_s_setprio(1);
#pragma unroll
      for (int ks2 = 0; ks2 < 2; ++ks2)
#pragma unroll
        for (int ni = 0; ni < 8; ++ni) {
          bf16x8 vf = *reinterpret_cast<const bf16x8*>(
              Vb + ((long)(ni * 16 + r) << 11) + kv * 64 + ks2 * 32 + g * 8);
          acc[ni] = __builtin_amdgcn_mfma_f32_16x16x32_bf16(pa[ks2], vf, acc[ni], 0, 0, 0);
        }
      __builtin_amdgcn_s_setprio(0);
    }

    // ---- epilogue for this q-tile
#pragma unroll
    for (int j = 0; j < 4; ++j) {
      float lt = lrow[j];
      lt += __shfl_xor(lt, 1);
      lt += __shfl_xor(lt, 2);
      lt += __shfl_xor(lt, 4);
      lt += __shfl_xor(lt, 8);
      float inv = 1.0f / lt;
#pragma unroll
      for (int ni = 0; ni < 8; ++ni) acc[ni][j] *= inv;
    }
#pragma unroll
    for (int ni = 0; ni < 8; ++ni) {
      int col = h * HD + ni * 16 + r;
#pragma unroll
      for (int j = 0; j < 4; ++j) {
        long row = qrow0 + g * 4 + j;
        AO[row * HID + col] = f2bf(acc[ni][j]);
      }
    }
  }
}

// ---------------- host launch ----------------
extern "C" void kernel_launch(void* const* d_in, const int* in_sizes, int n_in,
                              void* d_out, int out_size, void* d_ws, size_t ws_size,
                              hipStream_t stream) {
  const float* x = (const float*)d_in[0];
  const float* wq = (const float*)d_in[1];
  const float* wk = (const float*)d_in[2];
  const float* wv = (const float*)d_in[3];
  const float* wo = (const float*)d_in[4];
  const float* kw = (const float*)d_in[5];
  float* out = (float*)d_out;

  ushort_t* ws = (ushort_t*)d_ws;
  ushort_t* xb = ws;                       // 4096x2048 bf16; reused as AO
  ushort_t* qkv = xb + 8388608;            // 4096x3072
  ushort_t* vt = qkv + 12582912;           // 1024x2048 (B*512 rows x 2048)
  ushort_t* wqkv = vt + 2097152;           // 3072x2048; later reused for wob

  // fused cast of x, wq, wk, wv (3670016 float4 units)
  cast_fused_kernel<<<14336, 256, 0, stream>>>(x, wq, wk, wv, xb, wqkv);

  // fused QKV projection: [4096][3072]
  gemm_bt_kernel<ushort_t><<<dim3(24, 32), 256, 0, stream>>>(xb, wqkv, qkv, 4096, QKV_N, 2048);

  // fused vectorized RoPE: q (fold kw*scale) + k
  rope_fused_kernel<<<2560, 256, 0, stream>>>(qkv, kw);

  transpose_v_kernel<<<512, 256, 0, stream>>>(qkv, vt);

  // wo cast reuses wqkv region (QKV GEMM done by stream order)
  ushort_t* wob = wqkv;
  cast_bf16_kernel<<<4096, 256, 0, stream>>>(wo, wob, 1048576);

  flash_attn_kernel<<<512, 256, 0, stream>>>(qkv, vt, xb);

  gemm_bt_kernel<float><<<dim3(16, 32), 256, 0, stream>>>(xb, wob, out, 4096, 2048, 2048);
}

// Round 11
// 342.024 us; speedup vs baseline: 1.4451x; 1.4451x over previous
//
#include <hip/hip_runtime.h>

#define S_LEN 2048
#define HID 2048
#define NH 16
#define HD 128
#define QKV_N 3072   // 2048 q + 512 k + 512 v
#define KCOL 2048
#define VCOL 2560

typedef unsigned short ushort_t;
using bf16x8 = __attribute__((ext_vector_type(8))) __bf16;
using f32x4 = __attribute__((ext_vector_type(4))) float;
using ushort8 = __attribute__((ext_vector_type(8))) unsigned short;
using ushort4v = __attribute__((ext_vector_type(4))) unsigned short;

__device__ __forceinline__ unsigned short f2bf(float f) {
  unsigned int u = __float_as_uint(f);
  unsigned int r = u + 0x7FFFu + ((u >> 16) & 1u);
  return (unsigned short)(r >> 16);
}
__device__ __forceinline__ float bf2f(unsigned short h) {
  return __uint_as_float(((unsigned int)h) << 16);
}

__device__ __forceinline__ void gload_lds16(const ushort_t* g, ushort_t* lds) {
  __builtin_amdgcn_global_load_lds(
      (const __attribute__((address_space(1))) unsigned int*)g,
      (__attribute__((address_space(3))) unsigned int*)lds, 16, 0, 0);
}

// ---------------- fused cast fp32 -> bf16 for x, wq, wk, wv ----------------
__global__ void cast_fused_kernel(const float* __restrict__ x, const float* __restrict__ wq,
                                  const float* __restrict__ wk, const float* __restrict__ wv,
                                  ushort_t* __restrict__ xb, ushort_t* __restrict__ wqkv) {
  int i = blockIdx.x * 256 + threadIdx.x;  // float4 units, total 3670016
  const float* src;
  ushort_t* dst;
  int li;
  if (i < 2097152) { src = x; dst = xb; li = i; }
  else if (i < 3145728) { src = wq; dst = wqkv; li = i - 2097152; }
  else if (i < 3407872) { src = wk; dst = wqkv + 4194304; li = i - 3145728; }
  else { src = wv; dst = wqkv + 5242880; li = i - 3407872; }
  float4 v = reinterpret_cast<const float4*>(src)[li];
  ushort4v o;
  o.x = f2bf(v.x); o.y = f2bf(v.y); o.z = f2bf(v.z); o.w = f2bf(v.w);
  reinterpret_cast<ushort4v*>(dst)[li] = o;
}

// ---------------- wo cast ----------------
__global__ void cast_bf16_kernel(const float* __restrict__ in, ushort_t* __restrict__ out, int n4) {
  int i = blockIdx.x * 256 + threadIdx.x;
  if (i >= n4) return;
  float4 v = reinterpret_cast<const float4*>(in)[i];
  ushort4v o;
  o.x = f2bf(v.x); o.y = f2bf(v.y); o.z = f2bf(v.z); o.w = f2bf(v.w);
  reinterpret_cast<ushort4v*>(out)[i] = o;
}

// ---------------- fused vectorized RoPE (q: fold kw*scale; k: plain) ----------------
__global__ void rope_fused_kernel(ushort_t* __restrict__ qkv, const float* __restrict__ kw) {
  int idx = blockIdx.x * 256 + threadIdx.x;  // 524288 q-threads + 131072 k-threads
  int row, colbase, j0;
  float wsc;
  if (idx < 524288) {
    row = idx >> 7;
    int p = idx & 127;
    int h = p >> 3;
    j0 = (p & 7) * 8;
    colbase = h * HD;
    wsc = 0.08838834764831845f * kw[h];
  } else {
    int t = idx - 524288;
    row = t >> 5;
    int p = t & 31;
    int h = p >> 3;
    j0 = (p & 7) * 8;
    colbase = KCOL + h * HD;
    wsc = 1.0f;
  }
  int s = row & (S_LEN - 1);
  long base = (long)row * QKV_N + colbase;
  ushort8 x1 = *reinterpret_cast<const ushort8*>(qkv + base + j0);
  ushort8 x2 = *reinterpret_cast<const ushort8*>(qkv + base + j0 + 64);
  ushort8 o1, o2;
#pragma unroll
  for (int e = 0; e < 8; ++e) {
    int j = j0 + e;
    float inv = __expf(-(float)j * (9.210340371976184f / 64.0f));
    float ang = (float)s * inv;
    float sv, cv;
    sincosf(ang, &sv, &cv);
    float a = bf2f(x1[e]), bb = bf2f(x2[e]);
    o1[e] = f2bf((a * cv - bb * sv) * wsc);
    o2[e] = f2bf((a * sv + bb * cv) * wsc);
  }
  *reinterpret_cast<ushort8*>(qkv + base + j0) = o1;
  *reinterpret_cast<ushort8*>(qkv + base + j0 + 64) = o2;
}

// ---------------- V transpose: qkv V-region [4096][512] -> vt[b*512+vd][2048] ----------------
__global__ __launch_bounds__(256) void transpose_v_kernel(const ushort_t* __restrict__ qkv,
                                                          ushort_t* __restrict__ vt) {
  __shared__ ushort_t T[64][76];
  int bid = blockIdx.x;  // 512 = 64 token-tiles x 8 dim-tiles
  int dd = bid & 7;
  int tt = bid >> 3;
  int tid = threadIdx.x;
#pragma unroll
  for (int it = 0; it < 2; ++it) {
    int c = tid + it * 256;
    int i = c >> 3, j8 = c & 7;
    ushort8 v = *reinterpret_cast<const ushort8*>(
        qkv + (long)(tt * 64 + i) * QKV_N + VCOL + dd * 64 + j8 * 8);
    *reinterpret_cast<ushort8*>(&T[i][j8 * 8]) = v;
  }
  __syncthreads();
#pragma unroll
  for (int it = 0; it < 2; ++it) {
    int c = tid + it * 256;
    int jd = c >> 3, sc = c & 7;
    ushort8 o;
#pragma unroll
    for (int e = 0; e < 8; ++e) o[e] = T[sc * 8 + e][jd];
    int token = tt * 64 + sc * 8;
    int b = token >> 11, s = token & (S_LEN - 1);
    int vd = dd * 64 + jd;
    *reinterpret_cast<ushort8*>(vt + ((long)(b * 512 + vd) << 11) + s) = o;
  }
}

// ---------------- 128^2 GEMM (kept for out-proj; 512 blocks fill the GPU) ----------------
__device__ __forceinline__ void store_c(ushort_t* p, float v) { *p = f2bf(v); }
__device__ __forceinline__ void store_c(float* p, float v) { *p = v; }

template <typename OT>
__global__ __launch_bounds__(256) void gemm_bt_kernel(const ushort_t* __restrict__ A,
                                                      const ushort_t* __restrict__ W,
                                                      OT* __restrict__ C, int M, int N, int K) {
  __shared__ ushort_t As[128 * 32];
  __shared__ ushort_t Bs[128 * 32];
  const int tid = threadIdx.x;
  const int l = tid & 63, w = tid >> 6;
  const int wr = w >> 1, wc = w & 1;
  const int r = l & 15, g = l >> 4;
  const long arow0 = (long)blockIdx.y * 128;
  const long brow0 = (long)blockIdx.x * 128;

  f32x4 acc[4][4] = {};

  const int c0 = tid, c1 = tid + 256;
  const ushort_t* a_src0 = A + (arow0 + (c0 >> 2)) * K + ((c0 & 3) << 3);
  const ushort_t* a_src1 = A + (arow0 + (c1 >> 2)) * K + ((c1 & 3) << 3);
  const ushort_t* b_src0 = W + (brow0 + (c0 >> 2)) * K + ((c0 & 3) << 3);
  const ushort_t* b_src1 = W + (brow0 + (c1 >> 2)) * K + ((c1 & 3) << 3);
  ushort_t* a_dst0 = &As[c0 * 8];
  ushort_t* a_dst1 = &As[c1 * 8];
  ushort_t* b_dst0 = &Bs[c0 * 8];
  ushort_t* b_dst1 = &Bs[c1 * 8];

  for (int kk = 0; kk < K; kk += 32) {
    gload_lds16(a_src0 + kk, a_dst0);
    gload_lds16(a_src1 + kk, a_dst1);
    gload_lds16(b_src0 + kk, b_dst0);
    gload_lds16(b_src1 + kk, b_dst1);
    __syncthreads();
    bf16x8 af[4], bw[4];
#pragma unroll
    for (int mi = 0; mi < 4; ++mi)
      af[mi] = *reinterpret_cast<const bf16x8*>(&As[(wr * 64 + mi * 16 + r) * 32 + g * 8]);
#pragma unroll
    for (int ni = 0; ni < 4; ++ni)
      bw[ni] = *reinterpret_cast<const bf16x8*>(&Bs[(wc * 64 + ni * 16 + r) * 32 + g * 8]);
#pragma unroll
    for (int mi = 0; mi < 4; ++mi)
#pragma unroll
      for (int ni = 0; ni < 4; ++ni)
        acc[mi][ni] = __builtin_amdgcn_mfma_f32_16x16x32_bf16(af[mi], bw[ni], acc[mi][ni], 0, 0, 0);
    __syncthreads();
  }

#pragma unroll
  for (int mi = 0; mi < 4; ++mi)
#pragma unroll
    for (int ni = 0; ni < 4; ++ni) {
      int col = (int)brow0 + wc * 64 + ni * 16 + r;
#pragma unroll
      for (int j = 0; j < 4; ++j) {
        int row = (int)arow0 + wr * 64 + mi * 16 + g * 4 + j;
        store_c(&C[(long)row * N + col], acc[mi][ni][j]);
      }
    }
}

// ---------------- 256^2 phase-split GEMM (QKV projection) ----------------
// 512 thr = 8 waves (2M x 4N), BK=64, full-tile dbuf (128 KB LDS), T2 chunk-XOR
// swizzle via pre-swizzled global source, 4 sub-phases/K-tile with
// s_barrier + lgkmcnt(0) + sched_barrier(0) (rule 18) + setprio (T5).
__device__ __forceinline__ void stage256(const ushort_t* __restrict__ Ag,
                                         const ushort_t* __restrict__ Wg, int kk, int K,
                                         ushort_t* __restrict__ AsB, ushort_t* __restrict__ BsB,
                                         int tid) {
#pragma unroll
  for (int i = 0; i < 4; ++i) {
    int c = tid + i * 512;
    int row = c >> 3, cc = c & 7;
    int scc = cc ^ (row & 7);
    gload_lds16(Ag + (long)row * K + kk + scc * 8, &AsB[c * 8]);
  }
#pragma unroll
  for (int i = 0; i < 4; ++i) {
    int c = tid + i * 512;
    int row = c >> 3, cc = c & 7;
    int scc = cc ^ (row & 7);
    gload_lds16(Wg + (long)row * K + kk + scc * 8, &BsB[c * 8]);
  }
}

__global__ __launch_bounds__(512, 2) void gemm256_kernel(const ushort_t* __restrict__ A,
                                                         const ushort_t* __restrict__ W,
                                                         ushort_t* __restrict__ C, int M, int N,
                                                         int K, int nbx) {
  __shared__ ushort_t As[2][256 * 64];  // 64 KB
  __shared__ ushort_t Bs[2][256 * 64];  // 64 KB

  // XCD-chunked bijective swizzle, A-panel-major (nwg % 8 == 0)
  const int nwg = (M >> 8) * nbx;
  const int cpx = nwg >> 3;
  const int o = (blockIdx.x & 7) * cpx + (blockIdx.x >> 3);
  const int bx = o % nbx, by = o / nbx;

  const int tid = threadIdx.x;
  const int l = tid & 63, w = tid >> 6;
  const int wr = w >> 2, wc = w & 3;
  const int r = l & 15, g = l >> 4;
  const long arow0 = (long)by * 256;
  const long bcol0 = (long)bx * 256;
  const ushort_t* Ag = A + arow0 * K;
  const ushort_t* Wg = W + bcol0 * K;

  f32x4 acc[8][4] = {};

  stage256(Ag, Wg, 0, K, As[0], Bs[0], tid);
  __syncthreads();
  int cur = 0;
  const int nt = K >> 6;

  for (int kt = 0; kt < nt; ++kt) {
    if (kt + 1 < nt) stage256(Ag, Wg, (kt + 1) << 6, K, As[cur ^ 1], Bs[cur ^ 1], tid);
    const ushort_t* AsC = As[cur];
    const ushort_t* BsC = Bs[cur];

    // B fragments once per K-tile (held across phases)
    bf16x8 bw[4][2];
#pragma unroll
    for (int ni = 0; ni < 4; ++ni)
#pragma unroll
      for (int ks = 0; ks < 2; ++ks) {
        int row = wc * 64 + ni * 16 + r;
        int chunk = (ks * 4 + g) ^ (r & 7);
        bw[ni][ks] = *reinterpret_cast<const bf16x8*>(&BsC[row * 64 + chunk * 8]);
      }
#pragma unroll
    for (int ph = 0; ph < 4; ++ph) {
      bf16x8 af[2][2];
#pragma unroll
      for (int m2 = 0; m2 < 2; ++m2)
#pragma unroll
        for (int ks = 0; ks < 2; ++ks) {
          int row = wr * 128 + (ph * 2 + m2) * 16 + r;
          int chunk = (ks * 4 + g) ^ (r & 7);
          af[m2][ks] = *reinterpret_cast<const bf16x8*>(&AsC[row * 64 + chunk * 8]);
        }
      __builtin_amdgcn_s_barrier();
      asm volatile("s_waitcnt lgkmcnt(0)" ::: "memory");
      __builtin_amdgcn_sched_barrier(0);
      __builtin_amdgcn_s_setprio(1);
#pragma unroll
      for (int m2 = 0; m2 < 2; ++m2)
#pragma unroll
        for (int ni = 0; ni < 4; ++ni)
#pragma unroll
          for (int ks = 0; ks < 2; ++ks)
            acc[ph * 2 + m2][ni] =
                __builtin_amdgcn_mfma_f32_16x16x32_bf16(af[m2][ks], bw[ni][ks],
                                                        acc[ph * 2 + m2][ni], 0, 0, 0);
      __builtin_amdgcn_s_setprio(0);
    }
    __syncthreads();  // drains stage vmcnt + buffer handoff
    cur ^= 1;
  }

#pragma unroll
  for (int mi = 0; mi < 8; ++mi)
#pragma unroll
    for (int ni = 0; ni < 4; ++ni) {
      long col = bcol0 + wc * 64 + ni * 16 + r;
#pragma unroll
      for (int j = 0; j < 4; ++j) {
        long row = arow0 + wr * 128 + mi * 16 + g * 4 + j;
        C[row * N + col] = f2bf(acc[mi][ni][j]);
      }
    }
}

// ---------------- flash attention helpers (round-6 verified) ----------------
__device__ __forceinline__ void stage_tile(const ushort_t* __restrict__ Kb,
                                           const ushort_t* __restrict__ Vb, int kv,
                                           ushort_t* __restrict__ KsBuf,
                                           ushort_t* __restrict__ VtsBuf, int tid) {
#pragma unroll
  for (int i = 0; i < 4; ++i) {
    int c = tid + i * 256;
    int krow = c >> 4, cc = c & 15;
    int scc = cc ^ (krow & 7);
    gload_lds16(Kb + (long)(kv * 64 + krow) * QKV_N + scc * 8, &KsBuf[c * 8]);
  }
#pragma unroll
  for (int i = 0; i < 4; ++i) {
    int c = tid + i * 256;
    int vrow = c >> 3, cc = c & 7;
    int scc = cc ^ (vrow & 7);
    gload_lds16(Vb + ((long)vrow << 11) + kv * 64 + scc * 8, &VtsBuf[c * 8]);
  }
}

// ---------------- causal GQA flash attention (round-6: pair-balanced, 2-phase) ----
__global__ __launch_bounds__(256) void flash_attn_kernel(const ushort_t* __restrict__ qkv,
                                                         const ushort_t* __restrict__ Vt,
                                                         ushort_t* __restrict__ AO) {
  __shared__ ushort_t Ks[2][64 * 128];
  __shared__ ushort_t Vts[2][128 * 64];
  __shared__ ushort_t Ps[4][16 * 64];

  const int d = blockIdx.x;
  const int o = (d & 7) * 64 + (d >> 3);
  const int pr = o & 15;
  const int h = (o >> 4) & 15;
  const int b = o >> 8;
  const int tid = threadIdx.x;
  const int l = tid & 63, w = tid >> 6;
  const int r = l & 15, g = l >> 4;
  const int kvh = h >> 2;

  const ushort_t* Qb = qkv + (long)b * S_LEN * QKV_N + h * HD;
  const ushort_t* Kb = qkv + (long)b * S_LEN * QKV_N + KCOL + kvh * HD;
  const ushort_t* Vb = Vt + ((long)(b * 512 + kvh * HD) << 11);

  for (int pi = 0; pi < 2; ++pi) {
    const int qt = pi ? (31 - pr) : pr;
    const int qg = qt * 64 + w * 16;
    const long qrow0 = (long)b * S_LEN + qg;

    bf16x8 qa[4];
#pragma unroll
    for (int ks = 0; ks < 4; ++ks)
      qa[ks] = *reinterpret_cast<const bf16x8*>(Qb + (long)(qg + r) * QKV_N + ks * 32 + g * 8);

    f32x4 acc[8] = {};
    float mrow[4], lrow[4];
#pragma unroll
    for (int j = 0; j < 4; ++j) { mrow[j] = -1e30f; lrow[j] = 0.f; }

    stage_tile(Kb, Vb, 0, Ks[0], Vts[0], tid);
    __syncthreads();
    int cur = 0;

    for (int kv = 0; kv <= qt; ++kv) {
      if (kv < qt) stage_tile(Kb, Vb, kv + 1, Ks[cur ^ 1], Vts[cur ^ 1], tid);
      const ushort_t* KsC = Ks[cur];
      const ushort_t* VtsC = Vts[cur];

      f32x4 s[4] = {};
#pragma unroll
      for (int ks = 0; ks < 4; ++ks) {
        bf16x8 kf[4];
#pragma unroll
        for (int ni = 0; ni < 4; ++ni) {
          int n = ni * 16 + r;
          int chunk = (ks * 4 + g) ^ (n & 7);
          kf[ni] = *reinterpret_cast<const bf16x8*>(
              reinterpret_cast<const char*>(KsC) + n * 256 + chunk * 16);
        }
#pragma unroll
        for (int ni = 0; ni < 4; ++ni)
          s[ni] = __builtin_amdgcn_mfma_f32_16x16x32_bf16(qa[ks], kf[ni], s[ni], 0, 0, 0);
      }
      if (kv == qt) {
#pragma unroll
        for (int ni = 0; ni < 4; ++ni) {
          int key = kv * 64 + ni * 16 + r;
#pragma unroll
          for (int j = 0; j < 4; ++j) {
            int rowq = qg + g * 4 + j;
            if (key > rowq) s[ni][j] = -1e30f;
          }
        }
      }
#pragma unroll
      for (int j = 0; j < 4; ++j) {
        float mx = fmaxf(fmaxf(s[0][j], s[1][j]), fmaxf(s[2][j], s[3][j]));
        mx = fmaxf(mx, __shfl_xor(mx, 1));
        mx = fmaxf(mx, __shfl_xor(mx, 2));
        mx = fmaxf(mx, __shfl_xor(mx, 4));
        mx = fmaxf(mx, __shfl_xor(mx, 8));
        float mo = mrow[j];
        float mn = fmaxf(mo, mx);
        float ef = __expf(mo - mn);
        mrow[j] = mn;
        float psum = 0.f;
#pragma unroll
        for (int ni = 0; ni < 4; ++ni) {
          float p = __expf(s[ni][j] - mn);
          s[ni][j] = p;
          psum += p;
        }
        lrow[j] = lrow[j] * ef + psum;
#pragma unroll
        for (int ni = 0; ni < 8; ++ni) acc[ni][j] *= ef;
      }
#pragma unroll
      for (int ni = 0; ni < 4; ++ni)
#pragma unroll
        for (int j = 0; j < 4; ++j) {
          int row = g * 4 + j;
          int chunk = (ni * 2 + (r >> 3)) ^ (row & 7);
          Ps[w][row * 64 + chunk * 8 + (r & 7)] = f2bf(s[ni][j]);
        }
#pragma unroll
      for (int ks2 = 0; ks2 < 2; ++ks2) {
        bf16x8 pa = *reinterpret_cast<const bf16x8*>(
            &Ps[w][r * 64 + (((ks2 * 4 + g) ^ (r & 7)) << 3)]);
#pragma unroll
        for (int ni = 0; ni < 8; ++ni) {
          int dd = ni * 16 + r;
          int chunk = (ks2 * 4 + g) ^ (dd & 7);
          bf16x8 vf = *reinterpret_cast<const bf16x8*>(
              reinterpret_cast<const char*>(VtsC) + dd * 128 + chunk * 16);
          acc[ni] = __builtin_amdgcn_mfma_f32_16x16x32_bf16(pa, vf, acc[ni], 0, 0, 0);
        }
      }
      __syncthreads();
      cur ^= 1;
    }

#pragma unroll
    for (int j = 0; j < 4; ++j) {
      float lt = lrow[j];
      lt += __shfl_xor(lt, 1);
      lt += __shfl_xor(lt, 2);
      lt += __shfl_xor(lt, 4);
      lt += __shfl_xor(lt, 8);
      float inv = 1.0f / lt;
#pragma unroll
      for (int ni = 0; ni < 8; ++ni) acc[ni][j] *= inv;
    }
#pragma unroll
    for (int ni = 0; ni < 8; ++ni) {
      int col = h * HD + ni * 16 + r;
#pragma unroll
      for (int j = 0; j < 4; ++j) {
        long row = qrow0 + g * 4 + j;
        AO[row * HID + col] = f2bf(acc[ni][j]);
      }
    }
  }
}

// ---------------- host launch ----------------
extern "C" void kernel_launch(void* const* d_in, const int* in_sizes, int n_in,
                              void* d_out, int out_size, void* d_ws, size_t ws_size,
                              hipStream_t stream) {
  const float* x = (const float*)d_in[0];
  const float* wq = (const float*)d_in[1];
  const float* wk = (const float*)d_in[2];
  const float* wv = (const float*)d_in[3];
  const float* wo = (const float*)d_in[4];
  const float* kw = (const float*)d_in[5];
  float* out = (float*)d_out;

  ushort_t* ws = (ushort_t*)d_ws;
  ushort_t* xb = ws;                       // 4096x2048 bf16; reused as AO
  ushort_t* qkv = xb + 8388608;            // 4096x3072
  ushort_t* vt = qkv + 12582912;           // 1024x2048
  ushort_t* wqkv = vt + 2097152;           // 3072x2048; later reused for wob

  // fused cast of x, wq, wk, wv
  cast_fused_kernel<<<14336, 256, 0, stream>>>(x, wq, wk, wv, xb, wqkv);

  // fused QKV projection via 256^2 phase-split GEMM: grid 192 blocks (12 x 16)
  gemm256_kernel<<<192, 512, 0, stream>>>(xb, wqkv, qkv, 4096, QKV_N, 2048, 12);

  // fused vectorized RoPE: q (fold kw*scale) + k
  rope_fused_kernel<<<2560, 256, 0, stream>>>(qkv, kw);

  transpose_v_kernel<<<512, 256, 0, stream>>>(qkv, vt);

  // wo cast reuses wqkv region (QKV GEMM done by stream order)
  ushort_t* wob = wqkv;
  cast_bf16_kernel<<<4096, 256, 0, stream>>>(wo, wob, 1048576);

  flash_attn_kernel<<<512, 256, 0, stream>>>(qkv, vt, xb);

  gemm_bt_kernel<float><<<dim3(16, 32), 256, 0, stream>>>(xb, wob, out, 4096, 2048, 2048);
}